// Round 3
// baseline (21418.820 us; speedup 1.0000x reference)
//
#include <hip/hip_runtime.h>
#include <cstdint>

#define T_STEPS 2048
#define BPG 16      // batches per group
#define HS 10       // hidden slices (wgs per group)
#define HU 40       // hidden units per wg
#define NCOL 160    // gate columns per wg (4 gates x HU, interleaved (unit<<2)|gate)
#define KTOT 404    // 400 hidden + 4 input
#define WROW 424    // LDS weight row pitch (bf16 elems)
#define HROW 416    // h buffer row pitch (bf16 elems) = 13*32
#define KCH 13      // K chunks of 32

typedef float f32x4 __attribute__((ext_vector_type(4)));
typedef short s16x8 __attribute__((ext_vector_type(8)));

__device__ __forceinline__ unsigned short f2bf(float f) {
  unsigned int u = __float_as_uint(f);
  unsigned int r = (u + 0x7FFFu + ((u >> 16) & 1u)) >> 16;
  return (unsigned short)r;
}
__device__ __forceinline__ float sigm(float x) { return 1.0f / (1.0f + __expf(-x)); }
__device__ __forceinline__ float tanh_f(float x) { return 1.0f - 2.0f / (__expf(2.0f * x) + 1.0f); }

// quad-perm DPP helpers (compile-time ctrl)
#define DPPF(x, ctrl) __int_as_float(__builtin_amdgcn_update_dpp(0, __float_as_int(x), (ctrl), 0xf, 0xf, true))

// ---------------------------------------------------------------------------
// Merged kernel. Blocks 0..79: encoder LSTM (8 batch-groups x 10 slices,
// persistent, per-wave-tag sync). Blocks 80..591: uw precompute (runs on the
// otherwise-idle CUs, fully hidden under the recurrence).
// Dynamic LDS: enc = Wl 135680 + bias 640 = 136320 B; uw uses a 33664 B slice.
// ---------------------------------------------------------------------------
__global__ __launch_bounds__(640, 1) void enc_uw_kernel(
    const float* __restrict__ x, const float* __restrict__ W_hh,
    const float* __restrict__ W_ih, const float* __restrict__ b_enc,
    unsigned short* __restrict__ hbuf, float* __restrict__ last_h,
    int* __restrict__ tags,
    const float* __restrict__ W_i2h, const float* __restrict__ b_i2h,
    const float* __restrict__ W_dec, const float* __restrict__ b_dec,
    float* __restrict__ uw)
{
  extern __shared__ char smem[];
  const int tid = threadIdx.x;
  const int bid = blockIdx.x;

  if (bid >= 80) {
    // ---------------- uw role ----------------
    float4* Wi = (float4*)smem;                       // 400 x 16B
    float4 (*WdT)[4] = (float4(*)[4])(smem + 6400);   // 400 x 4 x 16B
    float* bi = (float*)(smem + 32000);               // 400 x 4B
    float* bd = (float*)(smem + 33600);               // 16 x 4B
    for (int i = tid; i < 400; i += 640) {
      Wi[i] = *(const float4*)(W_i2h + (size_t)i * 4);
      bi[i] = b_i2h[i];
    }
    for (int i = tid; i < 6400; i += 640) {
      int gq = i & 15, hh = i >> 4;
      ((float*)&WdT[hh][0])[gq] = W_dec[(size_t)gq * 400 + hh];
    }
    if (tid < 16) bd[tid] = b_dec[tid];
    __syncthreads();
    if (tid < 512) {
      const int pos = (bid - 80) * 512 + tid;
      float4 xv = *(const float4*)(x + (size_t)pos * 4);
      float a[16];
#pragma unroll
      for (int qq = 0; qq < 16; ++qq) a[qq] = bd[qq];
      for (int hh = 0; hh < 400; ++hh) {
        float4 wv = Wi[hh];
        float u = fmaxf(wv.x * xv.x + wv.y * xv.y + wv.z * xv.z + wv.w * xv.w + bi[hh], 0.f);
#pragma unroll
        for (int q4 = 0; q4 < 4; ++q4) {
          float4 d = WdT[hh][q4];
          a[q4 * 4 + 0] = fmaf(d.x, u, a[q4 * 4 + 0]);
          a[q4 * 4 + 1] = fmaf(d.y, u, a[q4 * 4 + 1]);
          a[q4 * 4 + 2] = fmaf(d.z, u, a[q4 * 4 + 2]);
          a[q4 * 4 + 3] = fmaf(d.w, u, a[q4 * 4 + 3]);
        }
      }
      float4* o = (float4*)(uw + (size_t)pos * 16);
#pragma unroll
      for (int q4 = 0; q4 < 4; ++q4)
        o[q4] = make_float4(a[q4 * 4], a[q4 * 4 + 1], a[q4 * 4 + 2], a[q4 * 4 + 3]);
    }
    return;
  }

  // ---------------- enc role ----------------
  unsigned short* Wl = (unsigned short*)smem;     // [NCOL][WROW] bf16
  float* bias_l = (float*)(smem + 135680);        // [NCOL]

  const int g = bid & 7;     // batch group (XCD-affine under round-robin)
  const int n = bid >> 3;    // hidden slice 0..9
  const int bbase = g * BPG;
  const int hbase = n * HU;

  // stage weights (bf16), col c = (unit_local<<2)|gate interleave:
  //   unit_local = 4*(c>>4) + ((c>>2)&3), gate = c&3
  for (int idx = tid; idx < NCOL * 101; idx += 640) {
    int c = idx / 101, kq = idx - c * 101;
    int gt = c & 3;
    int u = 4 * (c >> 4) + ((c >> 2) & 3);
    int row = gt * 400 + hbase + u;
    int k0 = kq * 4;
    float4 w;
    if (k0 < 400) w = *(const float4*)(W_hh + (size_t)row * 400 + k0);
    else          w = *(const float4*)(W_ih + (size_t)row * 4);
    unsigned short* dst = Wl + c * WROW + k0;
    dst[0] = f2bf(w.x); dst[1] = f2bf(w.y); dst[2] = f2bf(w.z); dst[3] = f2bf(w.w);
  }
  for (int idx = tid; idx < NCOL * (WROW - KTOT); idx += 640) {
    int c = idx / (WROW - KTOT), kk = KTOT + (idx % (WROW - KTOT));
    Wl[c * WROW + kk] = 0;
  }
  if (tid < NCOL) {
    int c = tid;
    bias_l[c] = b_enc[(c & 3) * 400 + hbase + 4 * (c >> 4) + ((c >> 2) & 3)];
  }

  int* tagsG = tags + g * 128;           // 100 tags per group, 512B stride
  const int wave = tid >> 6, lane = tid & 63;
  const int myTag = n * 10 + wave;

  // initial publication: x_0 (slice 0, wave 0 lanes 0..15); h_0 zeros from memset
  if (n == 0 && tid < 16) {
    float4 xv = *(const float4*)(x + (size_t)(bbase + tid) * T_STEPS * 4);
    unsigned int lo = f2bf(xv.x) | ((unsigned int)f2bf(xv.y) << 16);
    unsigned int hi = f2bf(xv.z) | ((unsigned int)f2bf(xv.w) << 16);
    unsigned long long v = lo | ((unsigned long long)hi << 32);
    __hip_atomic_store((unsigned long long*)(hbuf + (size_t)(bbase + tid) * HROW + 400),
                       v, __ATOMIC_RELAXED, __HIP_MEMORY_SCOPE_AGENT);
  }
  asm volatile("s_waitcnt vmcnt(0)" ::: "memory");
  if (lane == 0)
    __hip_atomic_store(&tagsG[myTag], 1, __ATOMIC_RELAXED, __HIP_MEMORY_SCOPE_AGENT);
  __syncthreads();

  const int cw = lane & 15, kgrp = lane >> 4;
  const int q = lane & 3, ul = (lane >> 2) & 3;
  const unsigned short* Bbase = Wl + (wave * 16 + cw) * WROW + kgrp * 8;
  const float bias = bias_l[wave * 16 + cw];
  const int batch = 4 * kgrp + q;          // 0..15 within group
  const int unit = 4 * wave + ul;          // 0..39 within slice
  float c_st = 0.f;

  for (int t = 0; t < T_STEPS; ++t) {
    const int p = t & 1;
    float4 xn;
    const bool do_x = (n == 0) && (tid < 16) && (t + 1 < T_STEPS);
    if (do_x) xn = *(const float4*)(x + ((size_t)(bbase + tid) * T_STEPS + (t + 1)) * 4);

    // wave 0 polls all 100 producer tags (relaxed, coalesced u64 loads)
    if (wave == 0) {
      const int tgt = t + 1;
      const unsigned long long* tp = (const unsigned long long*)tagsG;
      bool ok;
      do {
        unsigned long long v = 0;
        if (lane < 50) v = __hip_atomic_load(&tp[lane], __ATOMIC_RELAXED, __HIP_MEMORY_SCOPE_AGENT);
        ok = (lane >= 50) || (((int)(unsigned int)v >= tgt) && ((int)(v >> 32) >= tgt));
      } while (!__all(ok));
    }
    __syncthreads();
    __builtin_amdgcn_fence(__ATOMIC_ACQUIRE, "agent");

    // GEMM: this wave's 16 interleaved gate-cols x 16 batches over K=416
    const unsigned short* Arow = hbuf + ((size_t)p * 128 + (bbase + cw)) * HROW + kgrp * 8;
    s16x8 av[KCH], bv[KCH];
#pragma unroll
    for (int kc = 0; kc < KCH; ++kc) {
      av[kc] = *(const s16x8*)(Arow + kc * 32);
      bv[kc] = *(const s16x8*)(Bbase + kc * 32);
    }
    f32x4 accA = {bias, bias, bias, bias};   // bias folded into C-init
    f32x4 accB = {0.f, 0.f, 0.f, 0.f};
#pragma unroll
    for (int kc = 0; kc < KCH - 1; kc += 2) {
      accA = __builtin_amdgcn_mfma_f32_16x16x32_bf16(av[kc], bv[kc], accA, 0, 0, 0);
      accB = __builtin_amdgcn_mfma_f32_16x16x32_bf16(av[kc + 1], bv[kc + 1], accB, 0, 0, 0);
    }
    accA = __builtin_amdgcn_mfma_f32_16x16x32_bf16(av[KCH - 1], bv[KCH - 1], accA, 0, 0, 0);
    f32x4 m = accA + accB;

    // 4x4 in-quad transpose: lane (quad q) ends with gates {i,f,g,o} of
    // (batch 4*kgrp+q, unit 4*wave+ul)
    const bool q0 = (q & 1), q1b = (q & 2);
    float sA = DPPF(q0 ? m[0] : m[1], 0xB1);
    float sB = DPPF(q0 ? m[2] : m[3], 0xB1);
    float n0 = q0 ? sA : m[0];
    float n1 = q0 ? m[1] : sA;
    float n2 = q0 ? sB : m[2];
    float n3 = q0 ? m[3] : sB;
    float tA = DPPF(q1b ? n0 : n2, 0x4E);
    float tB = DPPF(q1b ? n1 : n3, 0x4E);
    float g0 = q1b ? tA : n0;
    float g1 = q1b ? tB : n1;
    float g2 = q1b ? n2 : tA;
    float g3 = q1b ? n3 : tB;

    float cn = sigm(g1) * c_st + sigm(g0) * tanh_f(g2);
    c_st = cn;
    float hn = sigm(g3) * tanh_f(cn);

    // publish h: pack unit-pairs to u32, write-through (sc0/sc1) to IF
    unsigned int hb = f2bf(hn);
    unsigned int pb = (unsigned int)__shfl_xor((int)hb, 4);
    if ((ul & 1) == 0) {
      unsigned int val = hb | (pb << 16);
      unsigned int* ptr = (unsigned int*)(hbuf +
          ((size_t)(p ^ 1) * 128 + (bbase + batch)) * HROW + hbase + 4 * wave + ul);
      __hip_atomic_store(ptr, val, __ATOMIC_RELAXED, __HIP_MEMORY_SCOPE_AGENT);
    }
    if (t == T_STEPS - 1)
      last_h[(size_t)(bbase + batch) * 400 + hbase + unit] = hn;
    if (do_x) {
      unsigned int lo = f2bf(xn.x) | ((unsigned int)f2bf(xn.y) << 16);
      unsigned int hi = f2bf(xn.z) | ((unsigned int)f2bf(xn.w) << 16);
      unsigned long long v = lo | ((unsigned long long)hi << 32);
      __hip_atomic_store((unsigned long long*)(hbuf +
          ((size_t)(p ^ 1) * 128 + (bbase + tid)) * HROW + 400),
          v, __ATOMIC_RELAXED, __HIP_MEMORY_SCOPE_AGENT);
    }
    // per-wave release: drain this wave's stores, then bump own tag
    asm volatile("s_waitcnt vmcnt(0)" ::: "memory");
    if (lane == 0)
      __hip_atomic_store(&tagsG[myTag], t + 2, __ATOMIC_RELAXED, __HIP_MEMORY_SCOPE_AGENT);
  }
}

// ---------------------------------------------------------------------------
// Fused head (mu/logvar/z/hd0) + decoder LSTM. grid = 128 (one per batch),
// block = 64. Decoder runs in lanes 0..3 with a depth-4 uw prefetch pipeline.
// ---------------------------------------------------------------------------
__global__ __launch_bounds__(64) void head_dec_kernel(
    const float* __restrict__ last_h, const float* __restrict__ eps,
    const float* __restrict__ W_mu, const float* __restrict__ b_mu,
    const float* __restrict__ W_lv, const float* __restrict__ b_lv,
    const float* __restrict__ W_l2h, const float* __restrict__ b_l2h,
    const float* __restrict__ Whh, const float* __restrict__ uw,
    float* __restrict__ out)
{
  const int b = blockIdx.x, tid = threadIdx.x;
  __shared__ float smu[20], slv[20], sz[20], hd4[4];
  const float4* h4 = (const float4*)(last_h + (size_t)b * 400);
  if (tid < 40) {
    const int o = tid % 20;
    const float4* w4 = (const float4*)((tid < 20 ? W_mu : W_lv) + (size_t)o * 400);
    float s = 0.f;
#pragma unroll 4
    for (int k = 0; k < 100; ++k) {
      float4 a = h4[k], w = w4[k];
      s += a.x * w.x + a.y * w.y + a.z * w.z + a.w * w.w;
    }
    if (tid < 20) { s += b_mu[o]; smu[o] = s; out[512 + b * 20 + o] = s; }
    else          { s += b_lv[o]; slv[o] = s; out[512 + 2560 + b * 20 + o] = s; }
  }
  __syncthreads();
  if (tid < 20) sz[tid] = smu[tid] + eps[b * 20 + tid] * __expf(0.5f * slv[tid]);
  __syncthreads();
  if (tid < 4) {
    float s = b_l2h[tid];
    for (int l = 0; l < 20; ++l) s += W_l2h[tid * 20 + l] * sz[l];
    hd4[tid] = s;
  }
  __syncthreads();
  if (tid < 4) {
    const int j = tid;
    float w[4][4];
#pragma unroll
    for (int gq = 0; gq < 4; ++gq)
#pragma unroll
      for (int k = 0; k < 4; ++k)
        w[gq][k] = Whh[(gq * 4 + j) * 4 + k];
    float h = hd4[j], c = 0.f;
    const float* up = uw + (size_t)b * T_STEPS * 16 + j;
    float pn[4][4];
#pragma unroll
    for (int s = 0; s < 4; ++s) {
      const float* u2 = up + (size_t)s * 16;
      pn[s][0] = u2[0]; pn[s][1] = u2[4]; pn[s][2] = u2[8]; pn[s][3] = u2[12];
    }
    for (int tb = 0; tb < T_STEPS; tb += 4) {
#pragma unroll
      for (int s = 0; s < 4; ++s) {
        float c0 = pn[s][0], c1 = pn[s][1], c2 = pn[s][2], c3 = pn[s][3];
        const int tn = tb + s + 4;
        if (tn < T_STEPS) {
          const float* u2 = up + (size_t)tn * 16;
          pn[s][0] = u2[0]; pn[s][1] = u2[4]; pn[s][2] = u2[8]; pn[s][3] = u2[12];
        }
        float h0 = DPPF(h, 0x00), h1 = DPPF(h, 0x55), h2 = DPPF(h, 0xAA), h3 = DPPF(h, 0xFF);
        c0 += w[0][0] * h0 + w[0][1] * h1 + w[0][2] * h2 + w[0][3] * h3;
        c1 += w[1][0] * h0 + w[1][1] * h1 + w[1][2] * h2 + w[1][3] * h3;
        c2 += w[2][0] * h0 + w[2][1] * h1 + w[2][2] * h2 + w[2][3] * h3;
        c3 += w[3][0] * h0 + w[3][1] * h1 + w[3][2] * h2 + w[3][3] * h3;
        c = sigm(c1) * c + sigm(c0) * tanh_f(c2);
        h = sigm(c3) * tanh_f(c);
      }
    }
    out[b * 4 + j] = h;
  }
}

// ---------------------------------------------------------------------------
// ws layout (bytes):
//   [0,      16384)  tags (8 groups x 128 ints; 100 used per group)
//   [16384,  229376) hbuf: 2 x 128 x 416 bf16 (zeroed -> h_0 = 0)
//   [229376, 434176) last_h: 128 x 400 f32
//   [524288, 17301504) uw: 128 x 2048 x 16 f32
// ---------------------------------------------------------------------------
extern "C" void kernel_launch(void* const* d_in, const int* in_sizes, int n_in,
                              void* d_out, int out_size, void* d_ws, size_t ws_size,
                              hipStream_t stream)
{
  (void)in_sizes; (void)n_in; (void)out_size; (void)ws_size;
  const float* x        = (const float*)d_in[0];
  const float* eps      = (const float*)d_in[1];
  const float* W_enc_ih = (const float*)d_in[2];
  const float* W_enc_hh = (const float*)d_in[3];
  const float* b_enc    = (const float*)d_in[4];
  const float* W_mu     = (const float*)d_in[5];
  const float* b_mu     = (const float*)d_in[6];
  const float* W_lv     = (const float*)d_in[7];
  const float* b_lv     = (const float*)d_in[8];
  const float* W_l2h    = (const float*)d_in[9];
  const float* b_l2h    = (const float*)d_in[10];
  const float* W_i2h    = (const float*)d_in[11];
  const float* b_i2h    = (const float*)d_in[12];
  const float* W_dec_ih = (const float*)d_in[13];
  const float* W_dec_hh = (const float*)d_in[14];
  const float* b_dec    = (const float*)d_in[15];
  float* out = (float*)d_out;
  char* ws = (char*)d_ws;
  int* tags = (int*)ws;
  unsigned short* hbuf = (unsigned short*)(ws + 16384);
  float* last_h = (float*)(ws + 229376);
  float* uw = (float*)(ws + 524288);

  static const int ENC_LDS = 136320;
  hipFuncSetAttribute((const void*)enc_uw_kernel,
                      hipFuncAttributeMaxDynamicSharedMemorySize, ENC_LDS);

  hipMemsetAsync(ws, 0, 229376, stream);   // tags + h_0 zeros
  enc_uw_kernel<<<592, 640, ENC_LDS, stream>>>(
      x, W_enc_hh, W_enc_ih, b_enc, hbuf, last_h, tags,
      W_i2h, b_i2h, W_dec_ih, b_dec, uw);
  head_dec_kernel<<<128, 64, 0, stream>>>(
      last_h, eps, W_mu, b_mu, W_lv, b_lv, W_l2h, b_l2h, W_dec_hh, uw, out);
}

// Round 5
// 6121.391 us; speedup vs baseline: 3.4990x; 3.4990x over previous
//
#include <hip/hip_runtime.h>
#include <cstdint>

#define T_STEPS 2048
#define BPG 16      // batches per group
#define HROW 416    // published row pitch in bf16 elems (832 B = 13*64)
#define KCH 13      // K chunks of 32
#define NPOS (128 * 2048)
#define POLL_CAP 16384

typedef float f32x4 __attribute__((ext_vector_type(4)));
typedef short s16x8 __attribute__((ext_vector_type(8)));
typedef unsigned int u32x4 __attribute__((ext_vector_type(4)));

__device__ __forceinline__ unsigned int f2bf(float f) {
  unsigned int u = __float_as_uint(f);
  return (u + 0x7FFFu + ((u >> 16) & 1u)) >> 16;
}
__device__ __forceinline__ float sigm(float x) { return 1.0f / (1.0f + __expf(-x)); }
__device__ __forceinline__ float tanh_f(float x) { return 1.0f - 2.0f / (__expf(2.0f * x) + 1.0f); }

#define DPPF(x, ctrl) __int_as_float(__builtin_amdgcn_update_dpp(0, __float_as_int(x), (ctrl), 0xf, 0xf, true))

// in-quad 4x4 transpose + LSTM gate update (validated numerically in r3)
__device__ __forceinline__ float gate_update(const f32x4 m, const int q, float& c_st) {
  const bool q0 = (q & 1), q1b = (q & 2);
  float sA = DPPF(q0 ? m[0] : m[1], 0xB1);
  float sB = DPPF(q0 ? m[2] : m[3], 0xB1);
  float n0 = q0 ? sA : m[0];
  float n1 = q0 ? m[1] : sA;
  float n2 = q0 ? sB : m[2];
  float n3 = q0 ? m[3] : sB;
  float tA = DPPF(q1b ? n0 : n2, 0x4E);
  float tB = DPPF(q1b ? n1 : n3, 0x4E);
  float g0 = q1b ? tA : n0;
  float g1 = q1b ? tB : n1;
  float g2 = q1b ? n2 : tA;
  float g3 = q1b ? n3 : tB;
  float cn = sigm(g1) * c_st + sigm(g0) * tanh_f(g2);
  c_st = cn;
  return sigm(g3) * tanh_f(cn);
}

__device__ __forceinline__ void st_sys_b128(void* p, u32x4 v) {
  asm volatile("global_store_dwordx4 %0, %1, off sc0 sc1" :: "v"(p), "v"(v) : "memory");
}

// ---------------------------------------------------------------------------
// Merged kernel, grid = 490 x 320 threads.
// Blocks 0..79: encoder LSTM. Block b -> group g = b&7, wg-slot s = b>>3.
//   Per wg: 5 waves, wave w owns octet o = s*5+w = canonical units 8o..8o+7.
//   Weights persist in VGPR B-fragments (k-axis follows the publish order).
//   Per step: bounded relaxed-agent tag poll -> cooperative A-tile staging
//   (16B system loads -> LDS) -> barrier -> 26 MFMA from LDS -> gate update
//   -> 16B-packed h publish (system stores) -> vmcnt(0) -> barrier -> 1 tag.
//   No fences, no inv, no wbl2 anywhere in the loop.
// Blocks 80..489: uw precompute (2 positions/thread), then exit.
// ---------------------------------------------------------------------------
__global__ __launch_bounds__(320, 2) void enc_uw_kernel(
    const float* __restrict__ x, const float* __restrict__ W_hh,
    const float* __restrict__ W_ih, const float* __restrict__ b_enc,
    unsigned short* __restrict__ hbuf, float* __restrict__ last_h,
    int* __restrict__ ctrl,
    const float* __restrict__ W_i2h, const float* __restrict__ b_i2h,
    const float* __restrict__ W_dec, const float* __restrict__ b_dec,
    float* __restrict__ uw)
{
  __shared__ char smem[33664];
  const int tid = threadIdx.x;
  const int bid = blockIdx.x;

  if (bid >= 80) {
    // ---------------- uw role ----------------
    float4* Wi = (float4*)smem;                       // [400]
    float4 (*WdT)[4] = (float4(*)[4])(smem + 6400);   // [400][4]
    float* bi = (float*)(smem + 32000);               // [400]
    float* bd = (float*)(smem + 33600);               // [16]
    for (int i = tid; i < 400; i += 320) {
      Wi[i] = *(const float4*)(W_i2h + (size_t)i * 4);
      bi[i] = b_i2h[i];
    }
    for (int i = tid; i < 6400; i += 320) {
      int gq = i & 15, hh = i >> 4;
      ((float*)&WdT[hh][0])[gq] = W_dec[(size_t)gq * 400 + hh];
    }
    if (tid < 16) bd[tid] = b_dec[tid];
    __syncthreads();
#pragma unroll
    for (int rep = 0; rep < 2; ++rep) {
      const int pos = (bid - 80) * 640 + rep * 320 + tid;
      if (pos < NPOS) {
        float4 xv = *(const float4*)(x + (size_t)pos * 4);
        float a[16];
#pragma unroll
        for (int qq = 0; qq < 16; ++qq) a[qq] = bd[qq];
        for (int hh = 0; hh < 400; ++hh) {
          float4 wv = Wi[hh];
          float u = fmaxf(wv.x * xv.x + wv.y * xv.y + wv.z * xv.z + wv.w * xv.w + bi[hh], 0.f);
#pragma unroll
          for (int q4 = 0; q4 < 4; ++q4) {
            float4 d = WdT[hh][q4];
            a[q4 * 4 + 0] = fmaf(d.x, u, a[q4 * 4 + 0]);
            a[q4 * 4 + 1] = fmaf(d.y, u, a[q4 * 4 + 1]);
            a[q4 * 4 + 2] = fmaf(d.z, u, a[q4 * 4 + 2]);
            a[q4 * 4 + 3] = fmaf(d.w, u, a[q4 * 4 + 3]);
          }
        }
        float4* o = (float4*)(uw + (size_t)pos * 16);
#pragma unroll
        for (int q4 = 0; q4 < 4; ++q4)
          o[q4] = make_float4(a[q4 * 4], a[q4 * 4 + 1], a[q4 * 4 + 2], a[q4 * 4 + 3]);
      }
    }
    return;
  }

  // ---------------- encoder role ----------------
  const int g = bid & 7, s = bid >> 3;
  const int wave = tid >> 6, lane = tid & 63;
  const int bbase = g * BPG;
  const int o = s * 5 + wave;                 // octet 0..49
  const int cw = lane & 15, kgrp = lane >> 4;
  const int q = lane & 3, a = (lane >> 2) & 3;
  const int gate = cw & 3, uloc = cw >> 2;
  const int ubase = 8 * o;
  const int batch = 4 * kgrp + q;
  int* tagsG = ctrl + g * 64;                 // 10 wg-tags per group

  // ---- stage weights into persistent VGPR B-fragments.
  // published k layout: octet og covers published [8og, 8og+8) with canonical
  // unit = 8*og + perm[j]; published 400..403 = x (W_ih), 404..415 = zero.
  const int perm[8] = {0, 4, 1, 5, 2, 6, 3, 7};
  s16x8 bv0[KCH], bv1[KCH];
#pragma unroll
  for (int tt = 0; tt < 2; ++tt) {
    const int row = gate * 400 + ubase + tt * 4 + uloc;
    const float* wr = W_hh + (size_t)row * 400;
#pragma unroll
    for (int kc = 0; kc < KCH; ++kc) {
      s16x8 bb;
#pragma unroll
      for (int i = 0; i < 8; ++i) {
        const int gk = kc * 32 + kgrp * 8 + i;
        float w;
        if (gk < 400)      w = wr[(size_t)(kc * 4 + kgrp) * 8 + perm[i]];
        else if (gk < 404) w = W_ih[(size_t)row * 4 + (gk - 400)];
        else               w = 0.f;
        bb[i] = (short)f2bf(w);
      }
      if (tt == 0) bv0[kc] = bb; else bv1[kc] = bb;
    }
  }
  const float bias0 = b_enc[gate * 400 + ubase + uloc];
  const float bias1 = b_enc[gate * 400 + ubase + 4 + uloc];

  // ---- initial publication: x_0 into parity-0 rows (h_0 = memset zeros)
  if (s == 0 && wave == 0 && a == 0) {
    float4 xv = *(const float4*)(x + (size_t)(bbase + batch) * T_STEPS * 4);
    u32x4 xp = {f2bf(xv.x) | (f2bf(xv.y) << 16), f2bf(xv.z) | (f2bf(xv.w) << 16), 0u, 0u};
    st_sys_b128((char*)(hbuf + (size_t)(bbase + batch) * HROW) + 800, xp);
  }
  asm volatile("s_waitcnt vmcnt(0)" ::: "memory");
  __syncthreads();
  if (wave == 0 && lane == 0)
    __hip_atomic_store(&tagsG[s], 1, __ATOMIC_RELAXED, __HIP_MEMORY_SCOPE_AGENT);

  float c0 = 0.f, c1 = 0.f;

  for (int t = 0; t < T_STEPS; ++t) {
    const int p = t & 1;
    // prefetch x_{t+1} (wg 0, wave 0, publisher lanes), plain cached load
    float4 xn;
    const bool do_x = (s == 0) && (wave == 0) && (a == 0) && (t + 1 < T_STEPS);
    if (do_x) xn = *(const float4*)(x + ((size_t)(bbase + batch) * T_STEPS + (t + 1)) * 4);

    // ---- bounded poll: all 10 wg-tags >= t+1 (relaxed agent loads, no inv)
    {
      const int tgt = t + 1;
      const unsigned long long* tp = (const unsigned long long*)tagsG;
      int iter = 0;
      bool ok;
      do {
        unsigned long long v = ~0ull;
        if (lane < 5)
          v = __hip_atomic_load(&tp[lane], __ATOMIC_RELAXED, __HIP_MEMORY_SCOPE_AGENT);
        ok = (lane >= 5) || (((int)(unsigned int)v >= tgt) && ((int)(v >> 32) >= tgt));
        if (++iter > POLL_CAP) break;     // degrade to wrong-answer, never hang
      } while (!__all(ok));
    }

    // ---- cooperative A-tile staging: 16 rows x 832B -> LDS (system loads)
    {
      char* dst = smem + p * 13312;
      const char* src = (const char*)(hbuf + ((size_t)p * 128 + bbase) * HROW);
      const int i0 = tid, i1 = tid + 320, i2 = tid + 640;
      const int r0 = i0 / 52, col0 = i0 % 52;
      const int r1 = i1 / 52, col1 = i1 % 52;
      const int r2 = i2 / 52, col2 = i2 % 52;
      const bool h2 = i2 < 832;
      u32x4 v0, v1, v2;
      asm volatile("global_load_dwordx4 %0, %1, off sc0 sc1"
                   : "=v"(v0) : "v"(src + r0 * 832 + col0 * 16) : "memory");
      asm volatile("global_load_dwordx4 %0, %1, off sc0 sc1"
                   : "=v"(v1) : "v"(src + r1 * 832 + col1 * 16) : "memory");
      if (h2)
        asm volatile("global_load_dwordx4 %0, %1, off sc0 sc1"
                     : "=v"(v2) : "v"(src + r2 * 832 + col2 * 16) : "memory");
      asm volatile("s_waitcnt vmcnt(0)" ::: "memory");
      *(u32x4*)(dst + r0 * 832 + col0 * 16) = v0;
      *(u32x4*)(dst + r1 * 832 + col1 * 16) = v1;
      if (h2) *(u32x4*)(dst + r2 * 832 + col2 * 16) = v2;
    }
    __syncthreads();   // B1: A-tile ready

    // ---- fragments from LDS + 26 MFMA (2 col-tiles x 13 chunks, dual chains)
    const char* At = smem + p * 13312 + cw * 832 + kgrp * 16;
    s16x8 av[KCH];
#pragma unroll
    for (int kc = 0; kc < KCH; ++kc) av[kc] = *(const s16x8*)(At + kc * 64);

    f32x4 acc00 = {bias0, bias0, bias0, bias0};
    f32x4 acc01 = {0.f, 0.f, 0.f, 0.f};
    f32x4 acc10 = {bias1, bias1, bias1, bias1};
    f32x4 acc11 = {0.f, 0.f, 0.f, 0.f};
#define MM(i)                                                                    \
    if ((i) & 1) {                                                               \
      acc01 = __builtin_amdgcn_mfma_f32_16x16x32_bf16(av[i], bv0[i], acc01, 0, 0, 0); \
      acc11 = __builtin_amdgcn_mfma_f32_16x16x32_bf16(av[i], bv1[i], acc11, 0, 0, 0); \
    } else {                                                                     \
      acc00 = __builtin_amdgcn_mfma_f32_16x16x32_bf16(av[i], bv0[i], acc00, 0, 0, 0); \
      acc10 = __builtin_amdgcn_mfma_f32_16x16x32_bf16(av[i], bv1[i], acc10, 0, 0, 0); \
    }
    MM(0) MM(1) MM(2) MM(3) MM(4) MM(5) MM(6) MM(7) MM(8) MM(9) MM(10) MM(11) MM(12)
#undef MM
    f32x4 m0 = acc00 + acc01;
    f32x4 m1 = acc10 + acc11;

    float hn0 = gate_update(m0, q, c0);   // unit ubase+a,   batch 4*kgrp+q
    float hn1 = gate_update(m1, q, c1);   // unit ubase+4+a

    // ---- publish: gather 4 packed u32 (a=0..3) into publisher lane, 16B store
    unsigned int v32 = f2bf(hn0) | (f2bf(hn1) << 16);
    const int srcb = lane & 51;           // zero the a-bits
    unsigned int w0 = (unsigned int)__shfl((int)v32, srcb);
    unsigned int w1 = (unsigned int)__shfl((int)v32, srcb + 4);
    unsigned int w2 = (unsigned int)__shfl((int)v32, srcb + 8);
    unsigned int w3 = (unsigned int)__shfl((int)v32, srcb + 12);
    if (a == 0) {
      char* rp = (char*)(hbuf + ((size_t)(p ^ 1) * 128 + bbase + batch) * HROW) + o * 16;
      u32x4 val = {w0, w1, w2, w3};
      st_sys_b128(rp, val);
      if (do_x) {
        u32x4 xp = {f2bf(xn.x) | (f2bf(xn.y) << 16), f2bf(xn.z) | (f2bf(xn.w) << 16), 0u, 0u};
        st_sys_b128(rp - o * 16 + 800, xp);
      }
    }
    if (t == T_STEPS - 1) {
      float* lp = last_h + (size_t)(bbase + batch) * 400 + ubase;
      lp[a] = hn0;
      lp[4 + a] = hn1;
    }
    asm volatile("s_waitcnt vmcnt(0)" ::: "memory");   // drain this wave's stores
    __syncthreads();   // B2: whole wg's publishes drained
    if (wave == 0 && lane == 0)
      __hip_atomic_store(&tagsG[s], t + 2, __ATOMIC_RELAXED, __HIP_MEMORY_SCOPE_AGENT);
  }
}

// ---------------------------------------------------------------------------
// Fused head (mu/logvar/z/hd0) + decoder LSTM. grid = 128, block = 64.
// ---------------------------------------------------------------------------
__global__ __launch_bounds__(64) void head_dec_kernel(
    const float* __restrict__ last_h, const float* __restrict__ eps,
    const float* __restrict__ W_mu, const float* __restrict__ b_mu,
    const float* __restrict__ W_lv, const float* __restrict__ b_lv,
    const float* __restrict__ W_l2h, const float* __restrict__ b_l2h,
    const float* __restrict__ Whh, const float* __restrict__ uw,
    float* __restrict__ out)
{
  const int b = blockIdx.x, tid = threadIdx.x;
  __shared__ float smu[20], slv[20], sz[20], hd4[4];
  const float4* h4 = (const float4*)(last_h + (size_t)b * 400);
  if (tid < 40) {
    const int o = tid % 20;
    const float4* w4 = (const float4*)((tid < 20 ? W_mu : W_lv) + (size_t)o * 400);
    float s = 0.f;
#pragma unroll 4
    for (int k = 0; k < 100; ++k) {
      float4 a = h4[k], w = w4[k];
      s += a.x * w.x + a.y * w.y + a.z * w.z + a.w * w.w;
    }
    if (tid < 20) { s += b_mu[o]; smu[o] = s; out[512 + b * 20 + o] = s; }
    else          { s += b_lv[o]; slv[o] = s; out[512 + 2560 + b * 20 + o] = s; }
  }
  __syncthreads();
  if (tid < 20) sz[tid] = smu[tid] + eps[b * 20 + tid] * __expf(0.5f * slv[tid]);
  __syncthreads();
  if (tid < 4) {
    float s = b_l2h[tid];
    for (int l = 0; l < 20; ++l) s += W_l2h[tid * 20 + l] * sz[l];
    hd4[tid] = s;
  }
  __syncthreads();
  if (tid < 4) {
    const int j = tid;
    float w[4][4];
#pragma unroll
    for (int gq = 0; gq < 4; ++gq)
#pragma unroll
      for (int k = 0; k < 4; ++k)
        w[gq][k] = Whh[(gq * 4 + j) * 4 + k];
    float h = hd4[j], c = 0.f;
    const float* up = uw + (size_t)b * T_STEPS * 16 + j;
    float pn[4][4];
#pragma unroll
    for (int ss = 0; ss < 4; ++ss) {
      const float* u2 = up + (size_t)ss * 16;
      pn[ss][0] = u2[0]; pn[ss][1] = u2[4]; pn[ss][2] = u2[8]; pn[ss][3] = u2[12];
    }
    for (int tb = 0; tb < T_STEPS; tb += 4) {
#pragma unroll
      for (int ss = 0; ss < 4; ++ss) {
        float c0g = pn[ss][0], c1g = pn[ss][1], c2g = pn[ss][2], c3g = pn[ss][3];
        const int tn = tb + ss + 4;
        if (tn < T_STEPS) {
          const float* u2 = up + (size_t)tn * 16;
          pn[ss][0] = u2[0]; pn[ss][1] = u2[4]; pn[ss][2] = u2[8]; pn[ss][3] = u2[12];
        }
        float h0 = DPPF(h, 0x00), h1 = DPPF(h, 0x55), h2 = DPPF(h, 0xAA), h3 = DPPF(h, 0xFF);
        c0g += w[0][0] * h0 + w[0][1] * h1 + w[0][2] * h2 + w[0][3] * h3;
        c1g += w[1][0] * h0 + w[1][1] * h1 + w[1][2] * h2 + w[1][3] * h3;
        c2g += w[2][0] * h0 + w[2][1] * h1 + w[2][2] * h2 + w[2][3] * h3;
        c3g += w[3][0] * h0 + w[3][1] * h1 + w[3][2] * h2 + w[3][3] * h3;
        c = sigm(c1g) * c + sigm(c0g) * tanh_f(c2g);
        h = sigm(c3g) * tanh_f(c);
      }
    }
    out[b * 4 + j] = h;
  }
}

// ---------------------------------------------------------------------------
// ws layout (bytes):
//   [0,     2048)   tags: 8 groups x 64 ints (10 used per group)
//   [16384, 229376) hbuf: 2 x 128 x 416 bf16 (zeroed -> h_0 = 0, k-pad = 0)
//   [229376,434176) last_h: 128 x 400 f32
//   [524288, ...)   uw: 128 x 2048 x 16 f32
// ---------------------------------------------------------------------------
extern "C" void kernel_launch(void* const* d_in, const int* in_sizes, int n_in,
                              void* d_out, int out_size, void* d_ws, size_t ws_size,
                              hipStream_t stream)
{
  (void)in_sizes; (void)n_in; (void)out_size; (void)ws_size;
  const float* x        = (const float*)d_in[0];
  const float* eps      = (const float*)d_in[1];
  const float* W_enc_ih = (const float*)d_in[2];
  const float* W_enc_hh = (const float*)d_in[3];
  const float* b_enc    = (const float*)d_in[4];
  const float* W_mu     = (const float*)d_in[5];
  const float* b_mu     = (const float*)d_in[6];
  const float* W_lv     = (const float*)d_in[7];
  const float* b_lv     = (const float*)d_in[8];
  const float* W_l2h    = (const float*)d_in[9];
  const float* b_l2h    = (const float*)d_in[10];
  const float* W_i2h    = (const float*)d_in[11];
  const float* b_i2h    = (const float*)d_in[12];
  const float* W_dec_ih = (const float*)d_in[13];
  const float* W_dec_hh = (const float*)d_in[14];
  const float* b_dec    = (const float*)d_in[15];
  float* out = (float*)d_out;
  char* ws = (char*)d_ws;
  int* ctrl = (int*)ws;
  unsigned short* hbuf = (unsigned short*)(ws + 16384);
  float* last_h = (float*)(ws + 229376);
  float* uw = (float*)(ws + 524288);

  hipMemsetAsync(ws, 0, 229376, stream);   // tags + h_0 zeros + k-pad zeros
  enc_uw_kernel<<<490, 320, 0, stream>>>(
      x, W_enc_hh, W_enc_ih, b_enc, hbuf, last_h, ctrl,
      W_i2h, b_i2h, W_dec_ih, b_dec, uw);
  head_dec_kernel<<<128, 64, 0, stream>>>(
      last_h, eps, W_mu, b_mu, W_lv, b_lv, W_l2h, b_l2h, W_dec_hh, uw, out);
}